// Round 5
// baseline (56.678 us; speedup 1.0000x reference)
//
#include <hip/hip_runtime.h>
#include <hip/hip_bf16.h>

#define VOCAB 128
#define HIDDEN 128

typedef float f32x4 __attribute__((ext_vector_type(4)));

// Fused prep kernel.
// Blocks 0..127: block o computes column o of both tables:
//   T1[v][o] = sum_h emb[v][h] * W[o][h]       + b[o]
//   T2[v][o] = sum_h emb[v][h] * W[o][128+h]
// Blocks 128..: pre-gather zz[e] = z[src[e]] | (z[dst[e]] << 16).
__global__ __launch_bounds__(128) void prep_kernel(
        const float* __restrict__ emb,
        const float* __restrict__ W,
        const float* __restrict__ b,
        const int* __restrict__ z,
        const int* __restrict__ src,
        const int* __restrict__ dst,
        float* __restrict__ T1,
        float* __restrict__ T2,
        unsigned int* __restrict__ zz,
        int E) {
    int t = threadIdx.x;
    if (blockIdx.x < VOCAB) {
        int o = blockIdx.x;
        __shared__ float es[VOCAB * (HIDDEN + 1)];
        // Stage emb: 16384 floats, coalesced float4 loads.
        for (int i = 0; i < (VOCAB * HIDDEN) / (128 * 4); ++i) {
            int f = (i * 128 + t) * 4;
            f32x4 val = *reinterpret_cast<const f32x4*>(emb + f);
            int v = f >> 7;
            int h = f & 127;
            float* d = es + v * (HIDDEN + 1) + h;
            d[0] = val.x; d[1] = val.y; d[2] = val.z; d[3] = val.w;
        }
        __syncthreads();
        int v = t;                                // one lane per vocab row
        const float* wr = W + o * (2 * HIDDEN);   // uniform -> scalar loads
        const float* er = es + v * (HIDDEN + 1);
        float s1 = 0.f, s2 = 0.f;
#pragma unroll 16
        for (int h = 0; h < HIDDEN; ++h) {
            float ev = er[h];
            s1 += ev * wr[h];
            s2 += ev * wr[HIDDEN + h];
        }
        T1[v * HIDDEN + o] = s1 + b[o];
        T2[v * HIDDEN + o] = s2;
    } else {
        // Pre-gather pass over edges.
        int nb = gridDim.x - VOCAB;
        int stride = nb * 128;
        for (int e = (blockIdx.x - VOCAB) * 128 + t; e < E; e += stride) {
            unsigned int zs = (unsigned int)z[src[e]];
            unsigned int zd = (unsigned int)z[dst[e]];
            zz[e] = zs | (zd << 16);
        }
    }
}

// 32 lanes per edge, one float4 per lane: each wave store instruction is
// 64 lanes x 16 B = 1024 B fully contiguous (whole cachelines) -> nt-safe.
// Chain: zz[e] (broadcast) -> T rows -> nt store.  4 VMEM per iter.
__global__ __launch_bounds__(256) void edge_gather_add(
        const unsigned int* __restrict__ zz,
        const float* __restrict__ T1,
        const float* __restrict__ T2,
        float* __restrict__ out,
        int E) {
    int total = E * 32;
    int stride = gridDim.x * blockDim.x;
    for (int idx = blockIdx.x * blockDim.x + threadIdx.x; idx < total; idx += stride) {
        int e = idx >> 5;
        int q = idx & 31;
        unsigned int p = zz[e];
        int zs = p & 0xFFFF;
        int zd = p >> 16;
        f32x4 a = *reinterpret_cast<const f32x4*>(T1 + zs * HIDDEN + q * 4);
        f32x4 c = *reinterpret_cast<const f32x4*>(T2 + zd * HIDDEN + q * 4);
        f32x4 r = a + c;
        __builtin_nontemporal_store(r, reinterpret_cast<f32x4*>(out + (size_t)e * HIDDEN + q * 4));
    }
}

extern "C" void kernel_launch(void* const* d_in, const int* in_sizes, int n_in,
                              void* d_out, int out_size, void* d_ws, size_t ws_size,
                              hipStream_t stream) {
    const int*   z    = (const int*)d_in[0];          // [N_NODES]
    const int*   ei   = (const int*)d_in[1];          // [2, E] row-major
    const float* emb  = (const float*)d_in[2];        // [128, 128]
    const float* W    = (const float*)d_in[3];        // [128, 256]
    const float* b    = (const float*)d_in[4];        // [128]
    float*       out  = (float*)d_out;                // [E, 128]

    int E = in_sizes[1] / 2;
    const int* src = ei;
    const int* dst = ei + E;

    float*        T1 = (float*)d_ws;                  // 64 KB
    float*        T2 = T1 + VOCAB * HIDDEN;           // 64 KB
    unsigned int* zz = (unsigned int*)(T2 + VOCAB * HIDDEN);  // E * 4 B

    prep_kernel<<<VOCAB + 896, 128, 0, stream>>>(emb, W, b, z, src, dst, T1, T2, zz, E);

    int block = 256;
    int grid = 2048;  // 8192 waves = 32/CU, grid-stride over E*32 units
    edge_gather_add<<<grid, block, 0, stream>>>(zz, T1, T2, out, E);
}